// Round 4
// baseline (182.520 us; speedup 1.0000x reference)
//
#include <hip/hip_runtime.h>

typedef __attribute__((ext_vector_type(8))) short short8;
typedef __attribute__((ext_vector_type(8))) __bf16 bf16x8;
typedef __attribute__((ext_vector_type(4))) float f32x4;
typedef __attribute__((ext_vector_type(4))) unsigned short ushort4_t;
typedef __attribute__((ext_vector_type(4))) unsigned int uint4_t;
typedef __attribute__((ext_vector_type(2))) unsigned int uint2_t;

#define NB   4096
#define NIN  4096
#define NX   4098
#define NC   128
#define NO   64
#define NA   64
#define NOUT 1024

__device__ __forceinline__ unsigned short f2bf(float f) {
  unsigned b = __builtin_bit_cast(unsigned, f);
  b += 0x7FFFu + ((b >> 16) & 1u);
  return (unsigned short)(b >> 16);
}
__device__ __forceinline__ float bf2f(unsigned short u) {
  return __builtin_bit_cast(float, (unsigned)u << 16);
}
// f32 -> e4m3fn byte: RNE, flush-to-zero below 2^-6, clamp at 448.
__device__ __forceinline__ unsigned f2e4m3(float f) {
  unsigned u = __builtin_bit_cast(unsigned, f);
  unsigned s = (u >> 24) & 0x80u;
  unsigned mag = u & 0x7fffffffu;
  mag = mag > 0x43E00000u ? 0x43E00000u : mag;   // clamp 448
  unsigned r = mag + 0x7FFFFu + ((mag >> 20) & 1u);
  int e = (int)(r >> 23) - 120;
  unsigned v = (e <= 0) ? 0u : (((unsigned)e << 3) | ((r >> 20) & 7u));
  return v | s;
}
// e4m3fn byte -> bf16 bits (flush E==0 to zero; encoder never emits subnormals)
__device__ __forceinline__ unsigned e4m32bf(unsigned f) {
  unsigned t = (((f & 0x7Fu) << 4) + 0x3C00u) | ((f & 0x80u) << 8);
  return (f & 0x78u) ? t : 0u;
}
// 8 fp8 bytes -> 8 bf16 (packed 4x u32)
__device__ __forceinline__ uint4_t dec8(uint2_t d) {
  uint4_t o;
#pragma unroll
  for (int k = 0; k < 4; ++k) {
    unsigned src = (k < 2) ? d[0] : d[1];
    unsigned sh = (k & 1) * 16;
    unsigned b0 = (src >> sh) & 0xFFu;
    unsigned b1 = (src >> (sh + 8)) & 0xFFu;
    o[k] = e4m32bf(b0) | (e4m32bf(b1) << 16);
  }
  return o;
}

// ---------------------------------------------------------------------------
// prep: x -> xT16 (bf16) AND xT8 (fp8); W -> bf16; const rows in both pools.
// ---------------------------------------------------------------------------
__global__ __launch_bounds__(256) void prep_kernel(
    const float* __restrict__ x, const float* __restrict__ W,
    unsigned short* __restrict__ xT16, unsigned char* __restrict__ xT8,
    unsigned short* __restrict__ Wb) {
  int bid = blockIdx.x, t = threadIdx.x;
  if (bid < 4096) {
    __shared__ unsigned short tile[64][68];
    int b0 = (bid >> 6) << 6, n0 = (bid & 63) << 6;
    int r = t >> 4, c4 = (t & 15) << 2;
#pragma unroll
    for (int rr = 0; rr < 4; ++rr) {
      int row = r + rr * 16;
      float4 v = *(const float4*)(x + (size_t)(b0 + row) * NIN + n0 + c4);
      tile[row][c4 + 0] = f2bf(v.x);
      tile[row][c4 + 1] = f2bf(v.y);
      tile[row][c4 + 2] = f2bf(v.z);
      tile[row][c4 + 3] = f2bf(v.w);
    }
    __syncthreads();
#pragma unroll
    for (int rr = 0; rr < 4; ++rr) {
      int nl = r + rr * 16;
      ushort4_t o;
      o.x = tile[c4 + 0][nl];
      o.y = tile[c4 + 1][nl];
      o.z = tile[c4 + 2][nl];
      o.w = tile[c4 + 3][nl];
      *(ushort4_t*)(xT16 + (size_t)(n0 + nl) * NB + b0 + c4) = o;
      unsigned pk = f2e4m3(bf2f(o.x)) | (f2e4m3(bf2f(o.y)) << 8) |
                    (f2e4m3(bf2f(o.z)) << 16) | (f2e4m3(bf2f(o.w)) << 24);
      *(unsigned*)(xT8 + (size_t)(n0 + nl) * NB + b0 + c4) = pk;
    }
  } else if (bid < 4096 + 256) {
    size_t i0 = (size_t)(bid - 4096) * 2048 + (size_t)t * 8;
    float4 v0 = *(const float4*)(W + i0);
    float4 v1 = *(const float4*)(W + i0 + 4);
    ushort4_t a, b;
    a.x = f2bf(v0.x); a.y = f2bf(v0.y); a.z = f2bf(v0.z); a.w = f2bf(v0.w);
    b.x = f2bf(v1.x); b.y = f2bf(v1.y); b.z = f2bf(v1.z); b.w = f2bf(v1.w);
    *(ushort4_t*)(Wb + i0) = a;
    *(ushort4_t*)(Wb + i0 + 4) = b;
  } else {
    int e = (bid - 4352) * 1024 + t * 4;
    int row = e >> 12, col = e & 4095;
    unsigned short v16 = (row == 0) ? (unsigned short)0 : (unsigned short)0x3F80;
    unsigned char  v8  = (row == 0) ? (unsigned char)0 : (unsigned char)0x38;
    ushort4_t o = {v16, v16, v16, v16};
    *(ushort4_t*)(xT16 + (size_t)(NIN + row) * NB + col) = o;
    *(unsigned*)(xT8 + (size_t)(NIN + row) * NB + col) = (unsigned)v8 * 0x01010101u;
  }
}

// ---------------------------------------------------------------------------
// mask: mark which buffer rows (c*64+o) the final gather needs. 1 block.
// ---------------------------------------------------------------------------
__global__ __launch_bounds__(1024) void mask_kernel(
    const int* __restrict__ oidx, unsigned char* __restrict__ mask) {
  int t = threadIdx.x;
#pragma unroll
  for (int i = t; i < NC * NO; i += 1024) mask[i] = 0;
  __syncthreads();
  if (t < NOUT) {
    int idx = oidx[t];
    if (idx >= NX) mask[idx - NX] = 1;
  }
}

// ---------------------------------------------------------------------------
// cycle: gather fp8 rows -> decode bf16 -> register 8x8 transpose -> swizzled
// LDS [b][a] -> MFMA. MODE 0: store fp8 (re-gathered). MODE 1: store bf16,
// only rows flagged in mask; MFMA skipped for o-groups with no flagged rows.
// LDS u16 addr(b,a) = b*64 + ((a>>3)^(b&7)^((b>>5)&7))*8 + (a&7).
// ---------------------------------------------------------------------------
template <int MODE>
__global__ __launch_bounds__(256) void cycle_kernel(
    const unsigned char* __restrict__ xT8, const unsigned short* __restrict__ Wb,
    const unsigned char* __restrict__ buf8p, void* __restrict__ outbuf,
    const int* __restrict__ axon, const unsigned char* __restrict__ mask,
    int first) {
  __shared__ __align__(16) unsigned short G[256 * 64];  // 32 KiB
  int c = blockIdx.y;
  int t = threadIdx.x;
  int b0 = blockIdx.x << 8;
  const int* arow = axon + (c << 6);

  // ---- stage ----
  {
    int ao = t >> 5, bo = t & 31;
    const int* ar = arow + ao * 8;
    uint4_t rows[8];
#pragma unroll
    for (int r = 0; r < 8; ++r) {
      int idx = ar[r];
      const unsigned char* s = nullptr;
      if (idx < NX)      s = xT8 + (size_t)idx * NB;
      else if (!first)   s = buf8p + (size_t)(idx - NX) * NB;
      if (s) rows[r] = dec8(*(const uint2_t*)(s + b0 + bo * 8));
      else   rows[r] = (uint4_t)(0u);
    }
    unsigned lo[4][4], hi[4][4];
#pragma unroll
    for (int p = 0; p < 4; ++p)
#pragma unroll
      for (int k = 0; k < 4; ++k) {
        unsigned wi = rows[2 * p][k], wj = rows[2 * p + 1][k];
        lo[p][k] = __builtin_amdgcn_perm(wj, wi, 0x05040100u);
        hi[p][k] = __builtin_amdgcn_perm(wj, wi, 0x07060302u);
      }
#pragma unroll
    for (int e = 0; e < 8; ++e) {
      int k = e >> 1;
      uint4_t col;
      if (e & 1) { col[0] = hi[0][k]; col[1] = hi[1][k]; col[2] = hi[2][k]; col[3] = hi[3][k]; }
      else       { col[0] = lo[0][k]; col[1] = lo[1][k]; col[2] = lo[2][k]; col[3] = lo[3][k]; }
      int b = bo * 8 + e;
      int sw = ao ^ (b & 7) ^ ((b >> 5) & 7);
      *(uint4_t*)&G[b * 64 + (sw << 3)] = col;
    }
  }
  __syncthreads();

  // ---- compute ----
  int lane = t & 63, w = t >> 6;
  int ln = lane & 15, g = lane >> 4;
  const unsigned short* wrow = Wb + ((size_t)c << 12);

  bool flj[4], grp[4];
#pragma unroll
  for (int j = 0; j < 4; ++j) {
    if (MODE == 1) {
      flj[j] = mask[(c << 6) + j * 16 + ln] != 0;
      grp[j] = __any((int)flj[j]);
    } else {
      flj[j] = true; grp[j] = true;
    }
  }

  f32x4 acc[4][4];
#pragma unroll
  for (int i = 0; i < 4; ++i)
#pragma unroll
    for (int j = 0; j < 4; ++j) acc[i][j] = (f32x4)(0.f);

#pragma unroll
  for (int ks = 0; ks < 2; ++ks) {
    short8 ag[4];
#pragma unroll
    for (int i = 0; i < 4; ++i) {
      int bl = (w << 6) + (i << 4) + ln;
      int c8 = (ks << 2) + g;
      int sw = c8 ^ (bl & 7) ^ ((bl >> 5) & 7);
      ag[i] = *(const short8*)&G[bl * 64 + (sw << 3)];
    }
#pragma unroll
    for (int j = 0; j < 4; ++j) {
      if (!grp[j]) continue;
      short8 bw = *(const short8*)(wrow + ((size_t)(j * 16 + ln) << 6) + ks * 32 + g * 8);
#pragma unroll
      for (int i = 0; i < 4; ++i)
        acc[i][j] = __builtin_amdgcn_mfma_f32_16x16x32_bf16(
            __builtin_bit_cast(bf16x8, ag[i]), __builtin_bit_cast(bf16x8, bw),
            acc[i][j], 0, 0, 0);
    }
  }

  // ---- store: frag(i,j) lane holds o=j*16+ln, b=b0+w*64+i*16+g*4+{0..3} ----
  int wb0 = b0 + (w << 6);
#pragma unroll
  for (int j = 0; j < 4; ++j) {
    size_t rowoff = ((size_t)((c << 6) + j * 16 + ln)) * NB + wb0;
    if (MODE == 0) {
      unsigned char* dst = (unsigned char*)outbuf;
#pragma unroll
      for (int i = 0; i < 4; ++i) {
        unsigned pk = 0;
#pragma unroll
        for (int r = 0; r < 4; ++r)
          pk |= f2e4m3(fmaxf(acc[i][j][r], 0.f)) << (r * 8);
        *(unsigned*)(dst + rowoff + i * 16 + (g << 2)) = pk;
      }
    } else {
      if (!flj[j]) continue;
      unsigned short* dst = (unsigned short*)outbuf;
#pragma unroll
      for (int i = 0; i < 4; ++i) {
        ushort4_t pk;
#pragma unroll
        for (int r = 0; r < 4; ++r) pk[r] = f2bf(fmaxf(acc[i][j][r], 0.f));
        *(ushort4_t*)(dst + rowoff + i * 16 + (g << 2)) = pk;
      }
    }
  }
}

// ---------------------------------------------------------------------------
// final: out[b][j] = f32(pool16[out_idx[j]][b]); LDS transpose for coalescing.
// ---------------------------------------------------------------------------
__global__ __launch_bounds__(256) void final_kernel(
    const unsigned short* __restrict__ xT16, const unsigned short* __restrict__ bufFin,
    const int* __restrict__ out_idx, float* __restrict__ out) {
  __shared__ unsigned short tile[256][66];
  int j0 = blockIdx.x << 6, b0 = blockIdx.y << 8;
  int t = threadIdx.x;
  {
    int jl = t >> 2, bq = t & 3;
    int idx = out_idx[j0 + jl];
    const unsigned short* src = (idx < NX) ? xT16 + (size_t)idx * NB
                                           : bufFin + (size_t)(idx - NX) * NB;
    int jcol = jl ^ (bq << 4);
#pragma unroll
    for (int k = 0; k < 8; ++k) {
      short8 v = *(const short8*)(src + b0 + bq * 64 + k * 8);
#pragma unroll
      for (int m = 0; m < 8; ++m)
        tile[bq * 64 + k * 8 + m][jcol] = (unsigned short)v[m];
    }
  }
  __syncthreads();
  {
    int j = t & 63, ws = t >> 6;
#pragma unroll
    for (int bb = 0; bb < 64; ++bb) {
      int b = bb * 4 + ws;
      int jc = j ^ ((b >> 6) << 4);
      out[(size_t)(b0 + b) * NOUT + j0 + j] = bf2f(tile[b][jc]);
    }
  }
}

// ---------------------------------------------------------------------------
extern "C" void kernel_launch(void* const* d_in, const int* in_sizes, int n_in,
                              void* d_out, int out_size, void* d_ws, size_t ws_size,
                              hipStream_t stream) {
  const float* x    = (const float*)d_in[0];
  const float* W    = (const float*)d_in[1];
  const int*   axon = (const int*)d_in[2];
  const int*   oidx = (const int*)d_in[3];
  float* out = (float*)d_out;

  const size_t XT16_B = (size_t)NX * NB * 2;      // 33,570,816
  const size_t XT8_B  = (size_t)NX * NB;          // 16,785,408
  const size_t WB_B   = (size_t)NC * NO * NA * 2; //  1,048,576
  const size_t MASK_B = 8192;
  const size_t BUF8_B = (size_t)NC * NO * NB;     // 33,554,432
  const size_t BUFF_B = (size_t)NC * NO * NB * 2; // 67,108,864
  if (ws_size < XT16_B + XT8_B + WB_B + MASK_B + BUF8_B + BUFF_B) return; // 152 MB

  char* ws = (char*)d_ws;
  unsigned short* xT16 = (unsigned short*)ws;
  unsigned char*  xT8  = (unsigned char*)(ws + XT16_B);
  unsigned short* Wb   = (unsigned short*)(ws + XT16_B + XT8_B);
  unsigned char*  mask = (unsigned char*)(ws + XT16_B + XT8_B + WB_B);
  unsigned char*  buf8A = (unsigned char*)(ws + XT16_B + XT8_B + WB_B + MASK_B);
  unsigned short* bufF  = (unsigned short*)(ws + XT16_B + XT8_B + WB_B + MASK_B + BUF8_B);
  unsigned char*  buf8B = (unsigned char*)bufF;  // aliases bufF; dead by cycle 4

  prep_kernel<<<4360, 256, 0, stream>>>(x, W, xT16, xT8, Wb);
  mask_kernel<<<1, 1024, 0, stream>>>(oidx, mask);
  dim3 cg(NB / 256, NC);
  cycle_kernel<0><<<cg, 256, 0, stream>>>(xT8, Wb, buf8A, buf8A, axon, mask, 1);
  cycle_kernel<0><<<cg, 256, 0, stream>>>(xT8, Wb, buf8A, buf8B, axon, mask, 0);
  cycle_kernel<0><<<cg, 256, 0, stream>>>(xT8, Wb, buf8B, buf8A, axon, mask, 0);
  cycle_kernel<1><<<cg, 256, 0, stream>>>(xT8, Wb, buf8A, bufF,  axon, mask, 0);
  final_kernel<<<dim3(NOUT / 64, NB / 256), 256, 0, stream>>>(xT16, bufF, oidx, out);
}

// Round 5
// 175.655 us; speedup vs baseline: 1.0391x; 1.0391x over previous
//
#include <hip/hip_runtime.h>

typedef __attribute__((ext_vector_type(8))) short short8;
typedef __attribute__((ext_vector_type(8))) __bf16 bf16x8;
typedef __attribute__((ext_vector_type(4))) float f32x4;
typedef __attribute__((ext_vector_type(4))) unsigned short ushort4_t;
typedef __attribute__((ext_vector_type(4))) unsigned int uint4_t;
typedef __attribute__((ext_vector_type(2))) unsigned int uint2_t;

#define NB   4096
#define NIN  4096
#define NX   4098
#define NC   128
#define NO   64
#define NA   64
#define NOUT 1024

__device__ __forceinline__ unsigned short f2bf(float f) {
  unsigned b = __builtin_bit_cast(unsigned, f);
  b += 0x7FFFu + ((b >> 16) & 1u);
  return (unsigned short)(b >> 16);
}
__device__ __forceinline__ float bf2f(unsigned short u) {
  return __builtin_bit_cast(float, (unsigned)u << 16);
}
// f32 -> e4m3fn byte: RNE, flush-to-zero below 2^-6, clamp at 448.
__device__ __forceinline__ unsigned f2e4m3(float f) {
  unsigned u = __builtin_bit_cast(unsigned, f);
  unsigned s = (u >> 24) & 0x80u;
  unsigned mag = u & 0x7fffffffu;
  mag = mag > 0x43E00000u ? 0x43E00000u : mag;   // clamp 448
  unsigned r = mag + 0x7FFFFu + ((mag >> 20) & 1u);
  int e = (int)(r >> 23) - 120;
  unsigned v = (e <= 0) ? 0u : (((unsigned)e << 3) | ((r >> 20) & 7u));
  return v | s;
}
// e4m3fn byte -> bf16 bits (flush E==0 to zero; encoder never emits subnormals)
__device__ __forceinline__ unsigned e4m32bf(unsigned f) {
  unsigned t = (((f & 0x7Fu) << 4) + 0x3C00u) | ((f & 0x80u) << 8);
  return (f & 0x78u) ? t : 0u;
}
// 8 fp8 bytes -> 8 bf16 (packed 4x u32)
__device__ __forceinline__ uint4_t dec8(uint2_t d) {
  uint4_t o;
#pragma unroll
  for (int k = 0; k < 4; ++k) {
    unsigned src = (k < 2) ? d[0] : d[1];
    unsigned sh = (k & 1) * 16;
    unsigned b0 = (src >> sh) & 0xFFu;
    unsigned b1 = (src >> (sh + 8)) & 0xFFu;
    o[k] = e4m32bf(b0) | (e4m32bf(b1) << 16);
  }
  return o;
}

// ---------------------------------------------------------------------------
// prep: x -> xT16 (bf16) AND xT8 (fp8); W -> bf16; const rows in both pools.
// ---------------------------------------------------------------------------
__global__ __launch_bounds__(256) void prep_kernel(
    const float* __restrict__ x, const float* __restrict__ W,
    unsigned short* __restrict__ xT16, unsigned char* __restrict__ xT8,
    unsigned short* __restrict__ Wb) {
  int bid = blockIdx.x, t = threadIdx.x;
  if (bid < 4096) {
    __shared__ unsigned short tile[64][68];
    int b0 = (bid >> 6) << 6, n0 = (bid & 63) << 6;
    int r = t >> 4, c4 = (t & 15) << 2;
#pragma unroll
    for (int rr = 0; rr < 4; ++rr) {
      int row = r + rr * 16;
      float4 v = *(const float4*)(x + (size_t)(b0 + row) * NIN + n0 + c4);
      tile[row][c4 + 0] = f2bf(v.x);
      tile[row][c4 + 1] = f2bf(v.y);
      tile[row][c4 + 2] = f2bf(v.z);
      tile[row][c4 + 3] = f2bf(v.w);
    }
    __syncthreads();
#pragma unroll
    for (int rr = 0; rr < 4; ++rr) {
      int nl = r + rr * 16;
      ushort4_t o;
      o.x = tile[c4 + 0][nl];
      o.y = tile[c4 + 1][nl];
      o.z = tile[c4 + 2][nl];
      o.w = tile[c4 + 3][nl];
      *(ushort4_t*)(xT16 + (size_t)(n0 + nl) * NB + b0 + c4) = o;
      unsigned pk = f2e4m3(bf2f(o.x)) | (f2e4m3(bf2f(o.y)) << 8) |
                    (f2e4m3(bf2f(o.z)) << 16) | (f2e4m3(bf2f(o.w)) << 24);
      *(unsigned*)(xT8 + (size_t)(n0 + nl) * NB + b0 + c4) = pk;
    }
  } else if (bid < 4096 + 256) {
    size_t i0 = (size_t)(bid - 4096) * 2048 + (size_t)t * 8;
    float4 v0 = *(const float4*)(W + i0);
    float4 v1 = *(const float4*)(W + i0 + 4);
    ushort4_t a, b;
    a.x = f2bf(v0.x); a.y = f2bf(v0.y); a.z = f2bf(v0.z); a.w = f2bf(v0.w);
    b.x = f2bf(v1.x); b.y = f2bf(v1.y); b.z = f2bf(v1.z); b.w = f2bf(v1.w);
    *(ushort4_t*)(Wb + i0) = a;
    *(ushort4_t*)(Wb + i0 + 4) = b;
  } else {
    int e = (bid - 4352) * 1024 + t * 4;
    int row = e >> 12, col = e & 4095;
    unsigned short v16 = (row == 0) ? (unsigned short)0 : (unsigned short)0x3F80;
    unsigned char  v8  = (row == 0) ? (unsigned char)0 : (unsigned char)0x38;
    ushort4_t o = {v16, v16, v16, v16};
    *(ushort4_t*)(xT16 + (size_t)(NIN + row) * NB + col) = o;
    *(unsigned*)(xT8 + (size_t)(NIN + row) * NB + col) = (unsigned)v8 * 0x01010101u;
  }
}

// ---------------------------------------------------------------------------
// mask: mark which buffer rows (c*64+o) the final gather needs. 1 block.
// ---------------------------------------------------------------------------
__global__ __launch_bounds__(1024) void mask_kernel(
    const int* __restrict__ oidx, unsigned char* __restrict__ mask) {
  int t = threadIdx.x;
#pragma unroll
  for (int i = t; i < NC * NO; i += 1024) mask[i] = 0;
  __syncthreads();
  if (t < NOUT) {
    int idx = oidx[t];
    if (idx >= NX) mask[idx - NX] = 1;
  }
}

// ---------------------------------------------------------------------------
// cycle v5: BT=1024, 512 threads (8 waves), grid (4, 128).
// Gather loads are 1 KB contiguous per instruction: wave w owns row-octet
// ao=w (uniform -> scalar pointers), lane bo holds 16 fp8 bytes per row.
// Stash (8 rows x 16 fp8) held in regs; 4 sub-phases each rebuild the
// verified v4 256-b swizzled LDS tile (32 KiB) and run MFMA + store.
// LDS u16 addr(b,a) = b*64 + ((a>>3)^(b&7)^((b>>5)&7))*8 + (a&7).
// MODE 0: store fp8 (re-gathered). MODE 1: store bf16, masked rows only.
// ---------------------------------------------------------------------------
template <int MODE>
__global__ __launch_bounds__(512) void cycle_kernel(
    const unsigned char* __restrict__ xT8, const unsigned short* __restrict__ Wb,
    const unsigned char* __restrict__ buf8p, void* __restrict__ outbuf,
    const int* __restrict__ axon, const unsigned char* __restrict__ mask,
    int first) {
  __shared__ __align__(16) unsigned short G[256 * 64];  // 32 KiB
  int c = blockIdx.y;
  int t = threadIdx.x;
  int b0 = blockIdx.x << 10;
  const int* arow = axon + (c << 6);

  int lane = t & 63, w = t >> 6;
  int ln = lane & 15, g = lane >> 4;
  int ao = w;       // row-octet, wave-uniform
  int bo = lane;    // 16-byte b-chunk within the 1 KB tile

  // ---- gather stash: 8 rows x 16 fp8 (1 KB contiguous per instr) ----
  uint4_t stash[8];
#pragma unroll
  for (int r = 0; r < 8; ++r) {
    int idx = arow[ao * 8 + r];
    const unsigned char* s = nullptr;
    if (idx < NX)      s = xT8 + (size_t)idx * NB;
    else if (!first)   s = buf8p + (size_t)(idx - NX) * NB;
    stash[r] = s ? *(const uint4_t*)(s + b0 + bo * 16) : (uint4_t)(0u);
  }

  // ---- W fragments hoisted once: bw[ks][j] ----
  const unsigned short* wrow = Wb + ((size_t)c << 12);
  short8 bw[2][4];
#pragma unroll
  for (int ks = 0; ks < 2; ++ks)
#pragma unroll
    for (int j = 0; j < 4; ++j)
      bw[ks][j] = *(const short8*)(wrow + ((size_t)(j * 16 + ln) << 6) + ks * 32 + g * 8);

  bool flj[4], grp[4];
#pragma unroll
  for (int j = 0; j < 4; ++j) {
    if (MODE == 1) {
      flj[j] = mask[(c << 6) + j * 16 + ln] != 0;
      grp[j] = __any((int)flj[j]);
    } else {
      flj[j] = true; grp[j] = true;
    }
  }

  for (int p = 0; p < 4; ++p) {
    if (p) __syncthreads();  // prior phase's reads done before overwrite

    // ---- stage phase p: lanes owning b-range [p*256, p*256+256) ----
    if ((bo >> 4) == p) {
#pragma unroll
      for (int h = 0; h < 2; ++h) {
        uint4_t rbf[8];
#pragma unroll
        for (int r = 0; r < 8; ++r) {
          uint2_t d;
          d[0] = stash[r][2 * h];
          d[1] = stash[r][2 * h + 1];
          rbf[r] = dec8(d);
        }
        unsigned lo[4][4], hi[4][4];
#pragma unroll
        for (int q = 0; q < 4; ++q)
#pragma unroll
          for (int k = 0; k < 4; ++k) {
            unsigned wi = rbf[2 * q][k], wj = rbf[2 * q + 1][k];
            lo[q][k] = __builtin_amdgcn_perm(wj, wi, 0x05040100u);
            hi[q][k] = __builtin_amdgcn_perm(wj, wi, 0x07060302u);
          }
#pragma unroll
        for (int e = 0; e < 8; ++e) {
          int k = e >> 1;
          uint4_t col;
          if (e & 1) { col[0] = hi[0][k]; col[1] = hi[1][k]; col[2] = hi[2][k]; col[3] = hi[3][k]; }
          else       { col[0] = lo[0][k]; col[1] = lo[1][k]; col[2] = lo[2][k]; col[3] = lo[3][k]; }
          int bl = ((bo & 15) << 4) + h * 8 + e;  // b-local within 256-tile
          int sw = ao ^ (bl & 7) ^ ((bl >> 5) & 7);
          *(uint4_t*)&G[bl * 64 + (sw << 3)] = col;
        }
      }
    }
    __syncthreads();

    // ---- compute: wave w covers b-local [w*32, w*32+32) ----
    f32x4 acc[2][4];
#pragma unroll
    for (int i = 0; i < 2; ++i)
#pragma unroll
      for (int j = 0; j < 4; ++j) acc[i][j] = (f32x4)(0.f);

#pragma unroll
    for (int ks = 0; ks < 2; ++ks) {
      short8 ag[2];
#pragma unroll
      for (int i = 0; i < 2; ++i) {
        int bl = (w << 5) + (i << 4) + ln;
        int c8 = (ks << 2) + g;
        int sw = c8 ^ (bl & 7) ^ ((bl >> 5) & 7);
        ag[i] = *(const short8*)&G[bl * 64 + (sw << 3)];
      }
#pragma unroll
      for (int j = 0; j < 4; ++j) {
        if (!grp[j]) continue;
#pragma unroll
        for (int i = 0; i < 2; ++i)
          acc[i][j] = __builtin_amdgcn_mfma_f32_16x16x32_bf16(
              __builtin_bit_cast(bf16x8, ag[i]), __builtin_bit_cast(bf16x8, bw[ks][j]),
              acc[i][j], 0, 0, 0);
      }
    }

    // ---- store: frag(i,j) lane: o=j*16+ln, b=pb+i*16+g*4+{0..3} ----
    int pb = b0 + (p << 8) + (w << 5);
#pragma unroll
    for (int j = 0; j < 4; ++j) {
      size_t rowoff = ((size_t)((c << 6) + j * 16 + ln)) * NB + pb;
      if (MODE == 0) {
        unsigned char* dst = (unsigned char*)outbuf;
#pragma unroll
        for (int i = 0; i < 2; ++i) {
          unsigned pk = 0;
#pragma unroll
          for (int r = 0; r < 4; ++r)
            pk |= f2e4m3(fmaxf(acc[i][j][r], 0.f)) << (r * 8);
          *(unsigned*)(dst + rowoff + i * 16 + (g << 2)) = pk;
        }
      } else {
        if (!flj[j]) continue;
        unsigned short* dst = (unsigned short*)outbuf;
#pragma unroll
        for (int i = 0; i < 2; ++i) {
          ushort4_t pk;
#pragma unroll
          for (int r = 0; r < 4; ++r) pk[r] = f2bf(fmaxf(acc[i][j][r], 0.f));
          *(ushort4_t*)(dst + rowoff + i * 16 + (g << 2)) = pk;
        }
      }
    }
  }
}

// ---------------------------------------------------------------------------
// final: out[b][j] = f32(pool16[out_idx[j]][b]); LDS transpose for coalescing.
// ---------------------------------------------------------------------------
__global__ __launch_bounds__(256) void final_kernel(
    const unsigned short* __restrict__ xT16, const unsigned short* __restrict__ bufFin,
    const int* __restrict__ out_idx, float* __restrict__ out) {
  __shared__ unsigned short tile[256][66];
  int j0 = blockIdx.x << 6, b0 = blockIdx.y << 8;
  int t = threadIdx.x;
  {
    int jl = t >> 2, bq = t & 3;
    int idx = out_idx[j0 + jl];
    const unsigned short* src = (idx < NX) ? xT16 + (size_t)idx * NB
                                           : bufFin + (size_t)(idx - NX) * NB;
    int jcol = jl ^ (bq << 4);
#pragma unroll
    for (int k = 0; k < 8; ++k) {
      short8 v = *(const short8*)(src + b0 + bq * 64 + k * 8);
#pragma unroll
      for (int m = 0; m < 8; ++m)
        tile[bq * 64 + k * 8 + m][jcol] = (unsigned short)v[m];
    }
  }
  __syncthreads();
  {
    int j = t & 63, ws = t >> 6;
#pragma unroll
    for (int bb = 0; bb < 64; ++bb) {
      int b = bb * 4 + ws;
      int jc = j ^ ((b >> 6) << 4);
      out[(size_t)(b0 + b) * NOUT + j0 + j] = bf2f(tile[b][jc]);
    }
  }
}

// ---------------------------------------------------------------------------
extern "C" void kernel_launch(void* const* d_in, const int* in_sizes, int n_in,
                              void* d_out, int out_size, void* d_ws, size_t ws_size,
                              hipStream_t stream) {
  const float* x    = (const float*)d_in[0];
  const float* W    = (const float*)d_in[1];
  const int*   axon = (const int*)d_in[2];
  const int*   oidx = (const int*)d_in[3];
  float* out = (float*)d_out;

  const size_t XT16_B = (size_t)NX * NB * 2;      // 33,570,816
  const size_t XT8_B  = (size_t)NX * NB;          // 16,785,408
  const size_t WB_B   = (size_t)NC * NO * NA * 2; //  1,048,576
  const size_t MASK_B = 8192;
  const size_t BUF8_B = (size_t)NC * NO * NB;     // 33,554,432
  const size_t BUFF_B = (size_t)NC * NO * NB * 2; // 67,108,864
  if (ws_size < XT16_B + XT8_B + WB_B + MASK_B + BUF8_B + BUFF_B) return; // 152 MB

  char* ws = (char*)d_ws;
  unsigned short* xT16 = (unsigned short*)ws;
  unsigned char*  xT8  = (unsigned char*)(ws + XT16_B);
  unsigned short* Wb   = (unsigned short*)(ws + XT16_B + XT8_B);
  unsigned char*  mask = (unsigned char*)(ws + XT16_B + XT8_B + WB_B);
  unsigned char*  buf8A = (unsigned char*)(ws + XT16_B + XT8_B + WB_B + MASK_B);
  unsigned short* bufF  = (unsigned short*)(ws + XT16_B + XT8_B + WB_B + MASK_B + BUF8_B);
  unsigned char*  buf8B = (unsigned char*)bufF;  // aliases bufF; dead by cycle 4

  prep_kernel<<<4360, 256, 0, stream>>>(x, W, xT16, xT8, Wb);
  mask_kernel<<<1, 1024, 0, stream>>>(oidx, mask);
  dim3 cg(NB / 1024, NC);
  cycle_kernel<0><<<cg, 512, 0, stream>>>(xT8, Wb, buf8A, buf8A, axon, mask, 1);
  cycle_kernel<0><<<cg, 512, 0, stream>>>(xT8, Wb, buf8A, buf8B, axon, mask, 0);
  cycle_kernel<0><<<cg, 512, 0, stream>>>(xT8, Wb, buf8B, buf8A, axon, mask, 0);
  cycle_kernel<1><<<cg, 512, 0, stream>>>(xT8, Wb, buf8A, bufF,  axon, mask, 0);
  final_kernel<<<dim3(NOUT / 64, NB / 256), 256, 0, stream>>>(xT16, bufF, oidx, out);
}

// Round 6
// 155.837 us; speedup vs baseline: 1.1712x; 1.1272x over previous
//
#include <hip/hip_runtime.h>

typedef __attribute__((ext_vector_type(8))) short short8;
typedef __attribute__((ext_vector_type(8))) __bf16 bf16x8;
typedef __attribute__((ext_vector_type(4))) float f32x4;
typedef __attribute__((ext_vector_type(4))) unsigned short ushort4_t;
typedef __attribute__((ext_vector_type(4))) unsigned int uint4_t;

#define NB   4096
#define NIN  4096
#define NX   4098
#define NC   128
#define NO   64
#define NA   64
#define NOUT 1024

__device__ __forceinline__ unsigned short f2bf(float f) {
  unsigned b = __builtin_bit_cast(unsigned, f);
  b += 0x7FFFu + ((b >> 16) & 1u);
  return (unsigned short)(b >> 16);
}
__device__ __forceinline__ float bf2f(unsigned short u) {
  return __builtin_bit_cast(float, (unsigned)u << 16);
}

// ---------------------------------------------------------------------------
// prep: transpose x (B x NIN f32) -> xT (NX x NB bf16), W f32 -> bf16,
// and fill the zero/one constant rows.
// ---------------------------------------------------------------------------
__global__ __launch_bounds__(256) void prep_kernel(
    const float* __restrict__ x, const float* __restrict__ W,
    unsigned short* __restrict__ xT, unsigned short* __restrict__ Wb) {
  int bid = blockIdx.x, t = threadIdx.x;
  if (bid < 4096) {
    __shared__ unsigned short tile[64][68];
    int b0 = (bid >> 6) << 6, n0 = (bid & 63) << 6;
    int r = t >> 4, c4 = (t & 15) << 2;
#pragma unroll
    for (int rr = 0; rr < 4; ++rr) {
      int row = r + rr * 16;
      float4 v = *(const float4*)(x + (size_t)(b0 + row) * NIN + n0 + c4);
      tile[row][c4 + 0] = f2bf(v.x);
      tile[row][c4 + 1] = f2bf(v.y);
      tile[row][c4 + 2] = f2bf(v.z);
      tile[row][c4 + 3] = f2bf(v.w);
    }
    __syncthreads();
#pragma unroll
    for (int rr = 0; rr < 4; ++rr) {
      int nl = r + rr * 16;
      ushort4_t o;
      o.x = tile[c4 + 0][nl];
      o.y = tile[c4 + 1][nl];
      o.z = tile[c4 + 2][nl];
      o.w = tile[c4 + 3][nl];
      *(ushort4_t*)(xT + (size_t)(n0 + nl) * NB + b0 + c4) = o;
    }
  } else if (bid < 4096 + 256) {
    size_t i0 = (size_t)(bid - 4096) * 2048 + (size_t)t * 8;
    float4 v0 = *(const float4*)(W + i0);
    float4 v1 = *(const float4*)(W + i0 + 4);
    ushort4_t a, b;
    a.x = f2bf(v0.x); a.y = f2bf(v0.y); a.z = f2bf(v0.z); a.w = f2bf(v0.w);
    b.x = f2bf(v1.x); b.y = f2bf(v1.y); b.z = f2bf(v1.z); b.w = f2bf(v1.w);
    *(ushort4_t*)(Wb + i0) = a;
    *(ushort4_t*)(Wb + i0 + 4) = b;
  } else {
    int e = (bid - 4352) * 1024 + t * 4;
    int row = e >> 12, col = e & 4095;
    unsigned short val = (row == 0) ? (unsigned short)0 : (unsigned short)0x3F80;
    ushort4_t o = {val, val, val, val};
    *(ushort4_t*)(xT + (size_t)(NIN + row) * NB + col) = o;
  }
}

// ---------------------------------------------------------------------------
// mask: mark which buffer rows (c*64+o) the final gather needs. 1 block.
// ---------------------------------------------------------------------------
__global__ __launch_bounds__(1024) void mask_kernel(
    const int* __restrict__ oidx, unsigned char* __restrict__ mask) {
  int t = threadIdx.x;
#pragma unroll
  for (int i = t; i < NC * NO; i += 1024) mask[i] = 0;
  __syncthreads();
  if (t < NOUT) {
    int idx = oidx[t];
    if (idx >= NX) mask[idx - NX] = 1;
  }
}

// ---------------------------------------------------------------------------
// cycle v6: v3's gather/LDS/MFMA + FULL-LINE write epilogue.
// Block = 256 thr = 4 waves, Btile = 256 b, one core c. bf16 throughout.
// Stage (verified v3): reg 8x8 transpose -> swizzled b-major LDS tile G,
//   addr_u16(b,a) = b*64 + ((a>>3)^(b&7)^((b>>5)&7))*8 + (a&7).
// Epilogue (NEW): acc -> OS LDS tile [64 rows][264 u16], barrier, then each
// wave stores whole rows: 64 lanes x 8 B = 512 B contiguous per instruction
// (full 128-B lines) instead of 16 rows x 32 B partial segments.
// MODE 1 (last cycle): store only rows flagged in mask (wave-uniform skip).
// ---------------------------------------------------------------------------
template <int MODE>
__global__ __launch_bounds__(256) void cycle_kernel(
    const unsigned short* __restrict__ xT, const unsigned short* __restrict__ Wb,
    const unsigned short* __restrict__ bufPrev, unsigned short* __restrict__ bufNext,
    const int* __restrict__ axon, const unsigned char* __restrict__ mask,
    int first) {
  // G tile: 256*64 u16 = 32 KiB. OS tile: 64*264 u16 = 33.8 KiB. Aliased.
  __shared__ __align__(16) unsigned short SM[64 * 264];
  int c = blockIdx.y;
  int t = threadIdx.x;
  int b0 = blockIdx.x << 8;
  const int* arow = axon + (c << 6);

  // ---- stage (v3, verified) ----
  {
    int ao = t >> 5, bo = t & 31;
    const int* ar = arow + ao * 8;
    uint4_t rows[8];
#pragma unroll
    for (int r = 0; r < 8; ++r) {
      int idx = ar[r];
      const unsigned short* s = nullptr;
      if (idx < NX)      s = xT + (size_t)idx * NB;
      else if (!first)   s = bufPrev + (size_t)(idx - NX) * NB;
      if (s) rows[r] = *(const uint4_t*)(s + b0 + bo * 8);
      else   rows[r] = (uint4_t)(0u);
    }
    unsigned lo[4][4], hi[4][4];
#pragma unroll
    for (int p = 0; p < 4; ++p)
#pragma unroll
      for (int k = 0; k < 4; ++k) {
        unsigned wi = rows[2 * p][k], wj = rows[2 * p + 1][k];
        lo[p][k] = __builtin_amdgcn_perm(wj, wi, 0x05040100u);
        hi[p][k] = __builtin_amdgcn_perm(wj, wi, 0x07060302u);
      }
#pragma unroll
    for (int e = 0; e < 8; ++e) {
      int k = e >> 1;
      uint4_t col;
      if (e & 1) { col[0] = hi[0][k]; col[1] = hi[1][k]; col[2] = hi[2][k]; col[3] = hi[3][k]; }
      else       { col[0] = lo[0][k]; col[1] = lo[1][k]; col[2] = lo[2][k]; col[3] = lo[3][k]; }
      int b = bo * 8 + e;
      int sw = ao ^ (b & 7) ^ ((b >> 5) & 7);
      *(uint4_t*)&SM[b * 64 + (sw << 3)] = col;
    }
  }
  __syncthreads();

  // ---- compute (v3, verified) ----
  int lane = t & 63, w = t >> 6;
  int ln = lane & 15, g = lane >> 4;
  const unsigned short* wrow = Wb + ((size_t)c << 12);

  f32x4 acc[4][4];
#pragma unroll
  for (int i = 0; i < 4; ++i)
#pragma unroll
    for (int j = 0; j < 4; ++j) acc[i][j] = (f32x4)(0.f);

#pragma unroll
  for (int ks = 0; ks < 2; ++ks) {
    short8 bw[4];
#pragma unroll
    for (int j = 0; j < 4; ++j)
      bw[j] = *(const short8*)(wrow + ((size_t)(j * 16 + ln) << 6) + ks * 32 + g * 8);

    short8 ag[4];
#pragma unroll
    for (int i = 0; i < 4; ++i) {
      int bl = (w << 6) + (i << 4) + ln;
      int c8 = (ks << 2) + g;
      int sw = c8 ^ (bl & 7) ^ ((bl >> 5) & 7);
      ag[i] = *(const short8*)&SM[bl * 64 + (sw << 3)];
    }

#pragma unroll
    for (int i = 0; i < 4; ++i)
#pragma unroll
      for (int j = 0; j < 4; ++j)
        acc[i][j] = __builtin_amdgcn_mfma_f32_16x16x32_bf16(
            __builtin_bit_cast(bf16x8, ag[i]), __builtin_bit_cast(bf16x8, bw[j]),
            acc[i][j], 0, 0, 0);
  }

  // ---- epilogue: stage C in LDS, then full-line row stores ----
  __syncthreads();  // all MFMA reads of G done; safe to overwrite as OS
  // frag(i,j): lane holds o = j*16+ln, bl = w*64 + i*16 + g*4 + {0..3}
#pragma unroll
  for (int j = 0; j < 4; ++j) {
    int o = j * 16 + ln;
#pragma unroll
    for (int i = 0; i < 4; ++i) {
      ushort4_t pk;
#pragma unroll
      for (int r = 0; r < 4; ++r) pk[r] = f2bf(fmaxf(acc[i][j][r], 0.f));
      *(ushort4_t*)&SM[o * 264 + (w << 6) + (i << 4) + (g << 2)] = pk;
    }
  }
  __syncthreads();
  // wave w stores rows {it*4+w}: 64 lanes x 8 B = 512 B contiguous per row
#pragma unroll
  for (int it = 0; it < 16; ++it) {
    int row = it * 4 + w;
    if (MODE == 1 && mask[(c << 6) + row] == 0) continue;  // wave-uniform
    ushort4_t v = *(const ushort4_t*)&SM[row * 264 + (lane << 2)];
    *(ushort4_t*)(bufNext + ((size_t)((c << 6) + row)) * NB + b0 + (lane << 2)) = v;
  }
}

// ---------------------------------------------------------------------------
// final: out[b][j] = f32(pool[out_idx[j]][b]); LDS transpose for coalescing.
// ---------------------------------------------------------------------------
__global__ __launch_bounds__(256) void final_kernel(
    const unsigned short* __restrict__ xT, const unsigned short* __restrict__ bufFin,
    const int* __restrict__ out_idx, float* __restrict__ out) {
  __shared__ unsigned short tile[256][66];
  int j0 = blockIdx.x << 6, b0 = blockIdx.y << 8;
  int t = threadIdx.x;
  {
    int jl = t >> 2, bq = t & 3;
    int idx = out_idx[j0 + jl];
    const unsigned short* src = (idx < NX) ? xT + (size_t)idx * NB
                                           : bufFin + (size_t)(idx - NX) * NB;
    int jcol = jl ^ (bq << 4);
#pragma unroll
    for (int k = 0; k < 8; ++k) {
      short8 v = *(const short8*)(src + b0 + bq * 64 + k * 8);
#pragma unroll
      for (int m = 0; m < 8; ++m)
        tile[bq * 64 + k * 8 + m][jcol] = (unsigned short)v[m];
    }
  }
  __syncthreads();
  {
    int j = t & 63, ws = t >> 6;
#pragma unroll
    for (int bb = 0; bb < 64; ++bb) {
      int b = bb * 4 + ws;
      int jc = j ^ ((b >> 6) << 4);
      out[(size_t)(b0 + b) * NOUT + j0 + j] = bf2f(tile[b][jc]);
    }
  }
}

// ---------------------------------------------------------------------------
extern "C" void kernel_launch(void* const* d_in, const int* in_sizes, int n_in,
                              void* d_out, int out_size, void* d_ws, size_t ws_size,
                              hipStream_t stream) {
  const float* x    = (const float*)d_in[0];
  const float* W    = (const float*)d_in[1];
  const int*   axon = (const int*)d_in[2];
  const int*   oidx = (const int*)d_in[3];
  float* out = (float*)d_out;

  const size_t XT_BYTES  = (size_t)NX * NB * 2;        // 33,570,816
  const size_t WB_BYTES  = (size_t)NC * NO * NA * 2;   //  1,048,576
  const size_t BUF_BYTES = (size_t)NC * NO * NB * 2;   // 67,108,864
  const size_t MASK_B    = 8192;
  if (ws_size < XT_BYTES + WB_BYTES + 2 * BUF_BYTES + MASK_B) return;

  char* ws = (char*)d_ws;
  unsigned short* xT   = (unsigned short*)ws;
  unsigned short* Wb   = (unsigned short*)(ws + XT_BYTES);
  unsigned short* bufA = (unsigned short*)(ws + XT_BYTES + WB_BYTES);
  unsigned short* bufB = (unsigned short*)(ws + XT_BYTES + WB_BYTES + BUF_BYTES);
  unsigned char*  mask = (unsigned char*)(ws + XT_BYTES + WB_BYTES + 2 * BUF_BYTES);

  prep_kernel<<<4360, 256, 0, stream>>>(x, W, xT, Wb);
  mask_kernel<<<1, 1024, 0, stream>>>(oidx, mask);
  dim3 cg(NB / 256, NC);
  cycle_kernel<0><<<cg, 256, 0, stream>>>(xT, Wb, bufB, bufA, axon, mask, 1);
  cycle_kernel<0><<<cg, 256, 0, stream>>>(xT, Wb, bufA, bufB, axon, mask, 0);
  cycle_kernel<0><<<cg, 256, 0, stream>>>(xT, Wb, bufB, bufA, axon, mask, 0);
  // cycle 4: only rows the final gather reads (mask), written into bufB.
  cycle_kernel<1><<<cg, 256, 0, stream>>>(xT, Wb, bufA, bufB, axon, mask, 0);
  final_kernel<<<dim3(NOUT / 64, NB / 256), 256, 0, stream>>>(xT, bufB, oidx, out);
}